// Round 5
// baseline (664.794 us; speedup 1.0000x reference)
//
#include <hip/hip_runtime.h>

#define kNW 4096
#define kTC 24
#define kCL 4       // outputs per chunk (word-LSTM)
#define kBURN 32    // burn-in steps before each chunk
#define NBLK 1024   // persistent grid: 4 blocks/CU x 256 CUs, co-resident by construction

// ws float offsets
#define XE_OFF   0u         // [2][128][128]  char input-proj tables (bias folded)
#define WH_OFF   32768u     // [2][4096][32]  char-LSTM final hidden per word
#define XP_OFF   294912u    // [4][4096][128] word-LSTM input projections (bias folded)
#define ENC_OFF  2392064u   // [2][4096][64]  sigmoid(bilstm) encodings
#define SYNC_OFF 2916352u   // u32 barrier slots (zeroed by k_init each call)

__device__ __forceinline__ float fsig(float x){
  return __builtin_amdgcn_rcpf(1.f + __builtin_amdgcn_exp2f(-1.44269504f * x));
}
__device__ __forceinline__ float ftanh_(float x){
  return fmaf(2.f, __builtin_amdgcn_rcpf(1.f + __builtin_amdgcn_exp2f(-2.88539008f * x)), -1.f);
}

__global__ void k_init(unsigned* scnt){
  if (threadIdx.x < 16) scnt[threadIdx.x] = 0u;
}

__device__ __forceinline__ void gsync(unsigned* cnt){
  __syncthreads();                       // all block stores issued (barrier drains vmcnt)
  if (threadIdx.x == 0){
    __hip_atomic_fetch_add(cnt, 1u, __ATOMIC_ACQ_REL, __HIP_MEMORY_SCOPE_AGENT);
    while (__hip_atomic_load(cnt, __ATOMIC_ACQUIRE, __HIP_MEMORY_SCOPE_AGENT) < NBLK)
      __builtin_amdgcn_s_sleep(2);
    __threadfence();                     // belt-and-suspenders L1/L2 inv before block reads
  }
  __syncthreads();
}

// ================= fused P0..P3 =================
__global__ __launch_bounds__(256, 4) void k_fused(
    const int* __restrict__ e_chars, const int* __restrict__ e_lens,
    const int* __restrict__ f_chars, const int* __restrict__ f_lens,
    const float* __restrict__ embed_e, const float* __restrict__ embed_f,
    const float* __restrict__ eC_ih, const float* __restrict__ eC_hh, const float* __restrict__ eC_b,
    const float* __restrict__ fC_ih, const float* __restrict__ fC_hh, const float* __restrict__ fC_b,
    const float* __restrict__ efw_ih, const float* __restrict__ efw_hh, const float* __restrict__ efw_b,
    const float* __restrict__ ebw_ih, const float* __restrict__ ebw_hh, const float* __restrict__ ebw_b,
    const float* __restrict__ ffw_ih, const float* __restrict__ ffw_hh, const float* __restrict__ ffw_b,
    const float* __restrict__ fbw_ih, const float* __restrict__ fbw_hh, const float* __restrict__ fbw_b,
    float* __restrict__ ws)
{
  int lane = threadIdx.x & 63;
  int wv   = threadIdx.x >> 6;               // wave in block 0..3
  int gw   = blockIdx.x * 4 + wv;            // global wave 0..4095
  unsigned* scnt = (unsigned*)ws + SYNC_OFF;
  __shared__ __align__(16) float hl[4][32];

  // ---------- P0: char input-proj tables (32768 dot-128, 8 per wave) ----------
  {
    #pragma unroll 2
    for (int i = 0; i < 8; ++i){
      int o = gw * 8 + i;                    // 0..32767
      int side = o >> 14, cg = o & 16383;
      int c = cg >> 7, g = cg & 127;
      const float* er = (side ? embed_f : embed_e) + c * 128;
      const float* wr = (side ? fC_ih   : eC_ih)   + g * 128;
      float p = er[lane] * wr[lane] + er[lane + 64] * wr[lane + 64];
      #pragma unroll
      for (int m = 1; m < 64; m <<= 1) p += __shfl_xor(p, m, 64);
      if (lane == 0) ws[XE_OFF + side * 16384 + cg] = (side ? fC_b : eC_b)[g] + p;
    }
  }
  gsync(scnt + 0);

  // ---------- P1: char LSTM, 2 words per wave ----------
  {
    int side = gw >> 11;
    const int* chars = side ? f_chars : e_chars;
    const int* lens  = side ? f_lens  : e_lens;
    const float* Whh = side ? fC_hh : eC_hh;
    const float* X   = ws + XE_OFF + side * 16384;
    float* wh        = ws + WH_OFF + side * 131072;

    float wA[32], wB[32];
    #pragma unroll
    for (int q = 0; q < 8; ++q){
      float4 a  = *(const float4*)(Whh + lane * 32 + q * 4);
      float4 b4 = *(const float4*)(Whh + (lane + 64) * 32 + q * 4);
      wA[q*4+0]=a.x;  wA[q*4+1]=a.y;  wA[q*4+2]=a.z;  wA[q*4+3]=a.w;
      wB[q*4+0]=b4.x; wB[q*4+1]=b4.y; wB[q*4+2]=b4.z; wB[q*4+3]=b4.w;
    }
    float kB = (lane < 32) ? -2.88539008f : -1.44269504f;
    float cB = (lane < 32) ? 2.f : 1.f;
    float dB = (lane < 32) ? -1.f : 0.f;

    for (int j = 0; j < 2; ++j){
      int word = ((gw & 2047) << 1) + j;
      if (lane < 32) hl[wv][lane] = 0.f;
      float cst = 0.f, h2 = 0.f;
      int len = __builtin_amdgcn_readfirstlane(lens[word]);
      int ch0 = __builtin_amdgcn_readfirstlane(chars[word * kTC]);
      float xa = X[ch0 * 128 + lane];
      float xb = X[ch0 * 128 + 64 + lane];
      for (int t = 0; t < len; ++t){
        float accA = xa, accB = xb;
        if (t + 1 < len){
          int cn = __builtin_amdgcn_readfirstlane(chars[word * kTC + t + 1]);
          xa = X[cn * 128 + lane];
          xb = X[cn * 128 + 64 + lane];
        }
        float hb[32];
        #pragma unroll
        for (int q = 0; q < 8; ++q){
          float4 hv = *(const float4*)(&hl[wv][q * 4]);
          hb[q*4+0]=hv.x; hb[q*4+1]=hv.y; hb[q*4+2]=hv.z; hb[q*4+3]=hv.w;
        }
        #pragma unroll
        for (int k = 0; k < 32; ++k){
          accA = fmaf(wA[k], hb[k], accA);
          accB = fmaf(wB[k], hb[k], accB);
        }
        float sA = fsig(accA);
        float sB = fmaf(cB, __builtin_amdgcn_rcpf(1.f + __builtin_amdgcn_exp2f(kB * accB)), dB);
        float fs = __shfl_xor(sA, 32, 64);
        float os = __shfl_xor(sB, 32, 64);
        cst = fmaf(fs, cst, sA * sB);
        h2  = os * ftanh_(cst);
        if (lane < 32) hl[wv][lane] = h2;
      }
      if (lane < 32) wh[word * 32 + lane] = h2;
    }
  }
  gsync(scnt + 1);

  // ---------- P2: word-LSTM input projections (4 words per wave) ----------
  {
    int dir = gw >> 10;
    const float* Wih = dir==0?efw_ih : dir==1?ebw_ih : dir==2?ffw_ih : fbw_ih;
    const float* bb  = dir==0?efw_b  : dir==1?ebw_b  : dir==2?ffw_b  : fbw_b;
    const float* wh  = ws + WH_OFF + (dir >> 1) * 131072;
    float* xp        = ws + XP_OFF + dir * 524288;

    float wA[32], wB[32];
    #pragma unroll
    for (int q = 0; q < 8; ++q){
      float4 a  = *(const float4*)(Wih + lane * 32 + q * 4);
      float4 b4 = *(const float4*)(Wih + (lane + 64) * 32 + q * 4);
      wA[q*4+0]=a.x;  wA[q*4+1]=a.y;  wA[q*4+2]=a.z;  wA[q*4+3]=a.w;
      wB[q*4+0]=b4.x; wB[q*4+1]=b4.y; wB[q*4+2]=b4.z; wB[q*4+3]=b4.w;
    }
    float bA = bb[lane], bB2 = bb[lane + 64];
    int w0 = (gw & 1023) << 2;
    #pragma unroll
    for (int j = 0; j < 4; ++j){
      int w = w0 + j;
      const float4* hp = (const float4*)(wh + (size_t)w * 32);
      float accA = bA, accB = bB2;
      #pragma unroll
      for (int q = 0; q < 8; ++q){
        float4 hv = hp[q];
        accA = fmaf(hv.x, wA[q*4+0], accA); accB = fmaf(hv.x, wB[q*4+0], accB);
        accA = fmaf(hv.y, wA[q*4+1], accA); accB = fmaf(hv.y, wB[q*4+1], accB);
        accA = fmaf(hv.z, wA[q*4+2], accA); accB = fmaf(hv.z, wB[q*4+2], accB);
        accA = fmaf(hv.w, wA[q*4+3], accA); accB = fmaf(hv.w, wB[q*4+3], accB);
      }
      xp[(size_t)w * 128 + lane]      = accA;
      xp[(size_t)w * 128 + 64 + lane] = accB;
    }
  }
  gsync(scnt + 2);

  // ---------- P3: word BiLSTM chunks, CL=4 / BURN=32 (36 serial steps) ----------
  {
    int dir = gw >> 10;
    const float* Whh = dir==0?efw_hh : dir==1?ebw_hh : dir==2?ffw_hh : fbw_hh;
    int side = dir >> 1, bwd = dir & 1;
    const float* xp = ws + XP_OFF + dir * 524288;
    float* enc = ws + ENC_OFF + side * 262144 + (bwd ? 32 : 0);

    float wA[32], wB[32];
    #pragma unroll
    for (int q = 0; q < 8; ++q){
      float4 a  = *(const float4*)(Whh + lane * 32 + q * 4);
      float4 b4 = *(const float4*)(Whh + (lane + 64) * 32 + q * 4);
      wA[q*4+0]=a.x;  wA[q*4+1]=a.y;  wA[q*4+2]=a.z;  wA[q*4+3]=a.w;
      wB[q*4+0]=b4.x; wB[q*4+1]=b4.y; wB[q*4+2]=b4.z; wB[q*4+3]=b4.w;
    }
    if (lane < 32) hl[wv][lane] = 0.f;
    float cst = 0.f;
    float kB = (lane < 32) ? -2.88539008f : -1.44269504f;
    float cB = (lane < 32) ? 2.f : 1.f;
    float dB = (lane < 32) ? -1.f : 0.f;

    int qk = gw & 1023;
    int tauOut = qk * kCL;
    int tau0   = tauOut - kBURN; if (tau0 < 0) tau0 = 0;
    int tauEnd = tauOut + kCL;

    auto POS = [&](int tau){ return bwd ? (kNW - 1 - tau) : tau; };

    auto STEP = [&](float accA0, float accB0, int tau){
      float hb[32];
      #pragma unroll
      for (int q = 0; q < 8; ++q){
        float4 hv = *(const float4*)(&hl[wv][q * 4]);
        hb[q*4+0]=hv.x; hb[q*4+1]=hv.y; hb[q*4+2]=hv.z; hb[q*4+3]=hv.w;
      }
      float pA0=0.f,pA1=0.f,pA2=0.f,pA3=0.f,pB0=0.f,pB1=0.f,pB2=0.f,pB3=0.f;
      #pragma unroll
      for (int k = 0; k < 8; ++k){
        pA0 = fmaf(wA[k],    hb[k],    pA0); pB0 = fmaf(wB[k],    hb[k],    pB0);
        pA1 = fmaf(wA[k+8],  hb[k+8],  pA1); pB1 = fmaf(wB[k+8],  hb[k+8],  pB1);
        pA2 = fmaf(wA[k+16], hb[k+16], pA2); pB2 = fmaf(wB[k+16], hb[k+16], pB2);
        pA3 = fmaf(wA[k+24], hb[k+24], pA3); pB3 = fmaf(wB[k+24], hb[k+24], pB3);
      }
      float accA = accA0 + ((pA0 + pA1) + (pA2 + pA3));
      float accB = accB0 + ((pB0 + pB1) + (pB2 + pB3));
      float sA = fsig(accA);
      float sB = fmaf(cB, __builtin_amdgcn_rcpf(1.f + __builtin_amdgcn_exp2f(kB * accB)), dB);
      float fs = __shfl_xor(sA, 32, 64);
      float os = __shfl_xor(sB, 32, 64);
      cst = fmaf(fs, cst, sA * sB);
      float h2 = os * ftanh_(cst);
      if (lane < 32){
        hl[wv][lane] = h2;
        if (tau >= tauOut) enc[POS(tau) * 64 + lane] = fsig(h2);
      }
    };

    float pa0, pb0, pa1, pb1;
    { int ip = POS(tau0);     pa0 = xp[ip*128 + lane]; pb0 = xp[ip*128 + 64 + lane]; }
    { int ip = POS(tau0 + 1); pa1 = xp[ip*128 + lane]; pb1 = xp[ip*128 + 64 + lane]; }
    for (int tau = tau0; tau < tauEnd; tau += 2){
      float a0 = pa0, q0 = pb0;
      if (tau + 2 < tauEnd){ int ip = POS(tau + 2); pa0 = xp[ip*128 + lane]; pb0 = xp[ip*128 + 64 + lane]; }
      STEP(a0, q0, tau);
      float a1 = pa1, q1 = pb1;
      if (tau + 3 < tauEnd){ int ip = POS(tau + 3); pa1 = xp[ip*128 + lane]; pb1 = xp[ip*128 + 64 + lane]; }
      STEP(a1, q1, tau + 1);
    }
  }
}

// ---------------- K4: out = f_enc @ e_enc.T  (K=64), 128x128 tiles ----------------
__global__ __launch_bounds__(256, 4) void k_mm(const float* __restrict__ ws, float* __restrict__ out)
{
  const float* e_enc = ws + ENC_OFF;
  const float* f_enc = ws + ENC_OFF + 262144;
  __shared__ __align__(16) float fS[64][128];   // [k][row] — broadcast reads
  __shared__ __align__(16) float eS[64][128];   // [k][col] — contiguous reads
  int t = threadIdx.x;
  int row0 = blockIdx.y * 128;
  int col0 = blockIdx.x * 128;
  {
    int r = t & 127, kh = t >> 7;
    const float* fsrc = f_enc + (size_t)(row0 + r) * 64 + kh * 32;
    const float* esrc = e_enc + (size_t)(col0 + r) * 64 + kh * 32;
    #pragma unroll
    for (int q = 0; q < 8; ++q){
      float4 v = *(const float4*)(fsrc + q * 4);
      int k = kh * 32 + q * 4;
      fS[k+0][r] = v.x; fS[k+1][r] = v.y; fS[k+2][r] = v.z; fS[k+3][r] = v.w;
      float4 u = *(const float4*)(esrc + q * 4);
      eS[k+0][r] = u.x; eS[k+1][r] = u.y; eS[k+2][r] = u.z; eS[k+3][r] = u.w;
    }
  }
  __syncthreads();
  int tx = t & 15, ty = t >> 4;
  int r0 = ty * 8, c0 = tx * 8;
  float acc[8][8];
  #pragma unroll
  for (int i = 0; i < 8; ++i)
    #pragma unroll
    for (int j = 0; j < 8; ++j) acc[i][j] = 0.f;

  #pragma unroll 4
  for (int k = 0; k < 64; ++k){
    float4 fa = *(const float4*)(&fS[k][r0]);
    float4 fb = *(const float4*)(&fS[k][r0 + 4]);
    float4 ea = *(const float4*)(&eS[k][c0]);
    float4 eb = *(const float4*)(&eS[k][c0 + 4]);
    float fr[8] = {fa.x, fa.y, fa.z, fa.w, fb.x, fb.y, fb.z, fb.w};
    float ec[8] = {ea.x, ea.y, ea.z, ea.w, eb.x, eb.y, eb.z, eb.w};
    #pragma unroll
    for (int i = 0; i < 8; ++i)
      #pragma unroll
      for (int j = 0; j < 8; ++j)
        acc[i][j] = fmaf(fr[i], ec[j], acc[i][j]);
  }
  #pragma unroll
  for (int i = 0; i < 8; ++i){
    float* dst = out + (size_t)(row0 + r0 + i) * 4096 + col0 + c0;
    *(float4*)(dst)     = make_float4(acc[i][0], acc[i][1], acc[i][2], acc[i][3]);
    *(float4*)(dst + 4) = make_float4(acc[i][4], acc[i][5], acc[i][6], acc[i][7]);
  }
}

extern "C" void kernel_launch(void* const* d_in, const int* in_sizes, int n_in,
                              void* d_out, int out_size, void* d_ws, size_t ws_size,
                              hipStream_t stream)
{
  const int* e_chars = (const int*)d_in[0];
  const int* e_lens  = (const int*)d_in[1];
  const int* f_chars = (const int*)d_in[2];
  const int* f_lens  = (const int*)d_in[3];
  // d_in[4] = diag (unused by reference)
  const float* embed_e = (const float*)d_in[5];
  const float* embed_f = (const float*)d_in[6];
  const float* eC_ih = (const float*)d_in[7];
  const float* eC_hh = (const float*)d_in[8];
  const float* eC_b  = (const float*)d_in[9];
  const float* fC_ih = (const float*)d_in[10];
  const float* fC_hh = (const float*)d_in[11];
  const float* fC_b  = (const float*)d_in[12];
  const float* efw_ih = (const float*)d_in[13];
  const float* efw_hh = (const float*)d_in[14];
  const float* efw_b  = (const float*)d_in[15];
  const float* ebw_ih = (const float*)d_in[16];
  const float* ebw_hh = (const float*)d_in[17];
  const float* ebw_b  = (const float*)d_in[18];
  const float* ffw_ih = (const float*)d_in[19];
  const float* ffw_hh = (const float*)d_in[20];
  const float* ffw_b  = (const float*)d_in[21];
  const float* fbw_ih = (const float*)d_in[22];
  const float* fbw_hh = (const float*)d_in[23];
  const float* fbw_b  = (const float*)d_in[24];
  float* ws  = (float*)d_ws;
  float* out = (float*)d_out;

  hipLaunchKernelGGL(k_init, dim3(1), dim3(64), 0, stream, (unsigned*)ws + SYNC_OFF);
  hipLaunchKernelGGL(k_fused, dim3(NBLK), dim3(256), 0, stream,
                     e_chars, e_lens, f_chars, f_lens, embed_e, embed_f,
                     eC_ih, eC_hh, eC_b, fC_ih, fC_hh, fC_b,
                     efw_ih, efw_hh, efw_b, ebw_ih, ebw_hh, ebw_b,
                     ffw_ih, ffw_hh, ffw_b, fbw_ih, fbw_hh, fbw_b, ws);
  hipLaunchKernelGGL(k_mm, dim3(32, 32), dim3(256), 0, stream, ws, out);
}

// Round 6
// 123.414 us; speedup vs baseline: 5.3867x; 5.3867x over previous
//
#include <hip/hip_runtime.h>

#define kNW 4096
#define kTC 24
#define kCL 8       // outputs per chunk (word-LSTM)
#define kBURN 40    // burn-in steps before each chunk

// ws layout (float offsets)
#define XE_OFF   0u         // [2][128][128]  char input-proj tables (bias folded)
#define WH_OFF   32768u     // [2][4096][32]  char-LSTM final hidden per word
#define XP_OFF   294912u    // [4][4096][128] word-LSTM input projections (bias folded)
#define ENC_OFF  2392064u   // [2][4096][64]  sigmoid(bilstm) encodings

__device__ __forceinline__ float fsig(float x){
  return __builtin_amdgcn_rcpf(1.f + __builtin_amdgcn_exp2f(-1.44269504f * x));
}
__device__ __forceinline__ float ftanh_(float x){
  return fmaf(2.f, __builtin_amdgcn_rcpf(1.f + __builtin_amdgcn_exp2f(-2.88539008f * x)), -1.f);
}

// ---------------- K0: char input-projection tables ----------------
__global__ __launch_bounds__(256) void k_tables(
    const float* __restrict__ embed_e, const float* __restrict__ embed_f,
    const float* __restrict__ Wih_e, const float* __restrict__ b_e,
    const float* __restrict__ Wih_f, const float* __restrict__ b_f,
    float* __restrict__ ws)
{
  int side = blockIdx.y;
  const float* embed = side ? embed_f : embed_e;
  const float* Wih   = side ? Wih_f   : Wih_e;
  const float* bb    = side ? b_f     : b_e;
  float* X = ws + XE_OFF + side * 16384;
  int id = blockIdx.x * 256 + threadIdx.x;   // 0..16383
  int c = id >> 7, g = id & 127;
  const float* er = embed + c * 128;
  const float* wr = Wih + g * 128;
  float acc = bb[g];
  #pragma unroll 8
  for (int v = 0; v < 128; ++v) acc = fmaf(er[v], wr[v], acc);
  X[id] = acc;
}

// ---------------- K1: char LSTM, one wave per word ----------------
// waves_per_eu(2,4): VGPR budget 256, occupancy target <=4/EU -> the 64-float
// weight arrays stay RESIDENT (round-2/5 counters proved the default target
// voluntarily spills them to scratch at VGPR=48/64).
__global__ __launch_bounds__(128) __attribute__((amdgpu_waves_per_eu(2, 4)))
void k_char(
    const int* __restrict__ e_chars, const int* __restrict__ e_lens,
    const int* __restrict__ f_chars, const int* __restrict__ f_lens,
    const float* __restrict__ Whh_e, const float* __restrict__ Whh_f,
    float* __restrict__ ws)
{
  int side = blockIdx.y;
  const int* chars = side ? f_chars : e_chars;
  const int* lens  = side ? f_lens  : e_lens;
  const float* Whh = side ? Whh_f : Whh_e;
  const float* X   = ws + XE_OFF + side * 16384;
  float* wh        = ws + WH_OFF + side * 131072;

  int lane = threadIdx.x & 63;
  int wv   = threadIdx.x >> 6;          // 0..1
  int word = blockIdx.x * 2 + wv;

  __shared__ __align__(16) float hl[2][32];

  // lane L holds Whh rows L (i or f gate) and L+64 (g or o gate)
  float wA[32], wB[32];
  #pragma unroll
  for (int q = 0; q < 8; ++q){
    float4 a  = *(const float4*)(Whh + lane * 32 + q * 4);
    float4 b4 = *(const float4*)(Whh + (lane + 64) * 32 + q * 4);
    wA[q*4+0]=a.x;  wA[q*4+1]=a.y;  wA[q*4+2]=a.z;  wA[q*4+3]=a.w;
    wB[q*4+0]=b4.x; wB[q*4+1]=b4.y; wB[q*4+2]=b4.z; wB[q*4+3]=b4.w;
  }
  if (lane < 32) hl[wv][lane] = 0.f;
  float cst = 0.f, h2 = 0.f;
  int len = __builtin_amdgcn_readfirstlane(lens[word]);
  float kB = (lane < 32) ? -2.88539008f : -1.44269504f;
  float cB = (lane < 32) ? 2.f : 1.f;
  float dB = (lane < 32) ? -1.f : 0.f;

  int ch0 = __builtin_amdgcn_readfirstlane(chars[word * kTC]);
  float xa = X[ch0 * 128 + lane];
  float xb = X[ch0 * 128 + 64 + lane];

  for (int t = 0; t < len; ++t){
    float accA = xa, accB = xb;
    if (t + 1 < len){
      int cn = __builtin_amdgcn_readfirstlane(chars[word * kTC + t + 1]);
      xa = X[cn * 128 + lane];
      xb = X[cn * 128 + 64 + lane];
    }
    float hb[32];
    #pragma unroll
    for (int q = 0; q < 8; ++q){
      float4 hv = *(const float4*)(&hl[wv][q * 4]);
      hb[q*4+0]=hv.x; hb[q*4+1]=hv.y; hb[q*4+2]=hv.z; hb[q*4+3]=hv.w;
    }
    #pragma unroll
    for (int k = 0; k < 32; ++k){
      accA = fmaf(wA[k], hb[k], accA);
      accB = fmaf(wB[k], hb[k], accB);
    }
    float sA = fsig(accA);
    float sB = fmaf(cB, __builtin_amdgcn_rcpf(1.f + __builtin_amdgcn_exp2f(kB * accB)), dB);
    float fs = __shfl_xor(sA, 32, 64);
    float os = __shfl_xor(sB, 32, 64);
    cst = fmaf(fs, cst, sA * sB);
    h2  = os * ftanh_(cst);
    if (lane < 32) hl[wv][lane] = h2;
  }
  if (lane < 32) wh[word * 32 + lane] = h2;
}

// ---------------- K2: word-LSTM input projections ----------------
// 128 blocks x 4 dirs; each block owns 32 words; thread owns gate g with its
// Wih row resident; h loads wave-uniform (broadcast), stores coalesced.
__global__ __launch_bounds__(256) __attribute__((amdgpu_waves_per_eu(2, 4)))
void k_proj(
    const float* __restrict__ Wih0, const float* __restrict__ b0,
    const float* __restrict__ Wih1, const float* __restrict__ b1,
    const float* __restrict__ Wih2, const float* __restrict__ b2,
    const float* __restrict__ Wih3, const float* __restrict__ b3,
    float* __restrict__ ws)
{
  int dir = blockIdx.y;
  const float* Wih = dir==0?Wih0 : dir==1?Wih1 : dir==2?Wih2 : Wih3;
  const float* bb  = dir==0?b0  : dir==1?b1  : dir==2?b2  : b3;
  int side = dir >> 1;
  const float* wh = ws + WH_OFF + side * 131072;
  float* xp = ws + XP_OFF + dir * 524288;

  int g  = threadIdx.x & 127;
  int wq = threadIdx.x >> 7;              // 0..1
  int w0 = blockIdx.x * 32 + wq * 16;     // 16 words per half-block

  float wreg[32];
  #pragma unroll
  for (int q = 0; q < 8; ++q){
    float4 v = *(const float4*)(Wih + g * 32 + q * 4);
    wreg[q*4+0]=v.x; wreg[q*4+1]=v.y; wreg[q*4+2]=v.z; wreg[q*4+3]=v.w;
  }
  float bias = bb[g];

  float4 hc[8], hn[8];
  auto LOADH = [&](float4 (&dst)[8], int w){
    const float4* p = (const float4*)(wh + (size_t)w * 32);
    #pragma unroll
    for (int q = 0; q < 8; ++q) dst[q] = p[q];
  };
  auto DOT = [&](const float4 (&hb)[8], int w){
    float acc = bias;
    #pragma unroll
    for (int q = 0; q < 8; ++q){
      acc = fmaf(hb[q].x, wreg[q*4+0], acc);
      acc = fmaf(hb[q].y, wreg[q*4+1], acc);
      acc = fmaf(hb[q].z, wreg[q*4+2], acc);
      acc = fmaf(hb[q].w, wreg[q*4+3], acc);
    }
    xp[(size_t)w * 128 + g] = acc;
  };

  LOADH(hc, w0);
  #pragma unroll
  for (int j = 0; j < 16; j += 2){
    if (j + 1 < 16) LOADH(hn, w0 + j + 1);
    DOT(hc, w0 + j);
    if (j + 1 < 16){
      if (j + 2 < 16) LOADH(hc, w0 + j + 2);
      DOT(hn, w0 + j + 1);
    }
  }
}

// ---------------- K3: word BiLSTM, chunked-parallel with burn-in ----------------
__global__ __launch_bounds__(64) __attribute__((amdgpu_waves_per_eu(2, 4)))
void k_word_par(
    const float* __restrict__ Whh0, const float* __restrict__ Whh1,
    const float* __restrict__ Whh2, const float* __restrict__ Whh3,
    float* __restrict__ ws)
{
  int qk  = blockIdx.x;              // chunk id 0..511
  int dir = blockIdx.y;              // 0..3
  const float* Whh = dir==0?Whh0 : dir==1?Whh1 : dir==2?Whh2 : Whh3;
  int side = dir >> 1, bwd = dir & 1;
  const float* xp = ws + XP_OFF + dir * 524288;
  float* enc = ws + ENC_OFF + side * 262144 + (bwd ? 32 : 0);
  int lane = threadIdx.x;

  __shared__ __align__(16) float hl[32];

  float wA[32], wB[32];
  #pragma unroll
  for (int q = 0; q < 8; ++q){
    float4 a  = *(const float4*)(Whh + lane * 32 + q * 4);
    float4 b4 = *(const float4*)(Whh + (lane + 64) * 32 + q * 4);
    wA[q*4+0]=a.x;  wA[q*4+1]=a.y;  wA[q*4+2]=a.z;  wA[q*4+3]=a.w;
    wB[q*4+0]=b4.x; wB[q*4+1]=b4.y; wB[q*4+2]=b4.z; wB[q*4+3]=b4.w;
  }
  if (lane < 32) hl[lane] = 0.f;
  float cst = 0.f;
  float kB = (lane < 32) ? -2.88539008f : -1.44269504f;
  float cB = (lane < 32) ? 2.f : 1.f;
  float dB = (lane < 32) ? -1.f : 0.f;

  int tauOut = qk * kCL;
  int tau0   = tauOut - kBURN; if (tau0 < 0) tau0 = 0;
  int tauEnd = tauOut + kCL;

  auto POS = [&](int tau){ return bwd ? (kNW - 1 - tau) : tau; };

  auto STEP = [&](float accA0, float accB0, int tau){
    float hb[32];
    #pragma unroll
    for (int q = 0; q < 8; ++q){
      float4 hv = *(const float4*)(&hl[q * 4]);
      hb[q*4+0]=hv.x; hb[q*4+1]=hv.y; hb[q*4+2]=hv.z; hb[q*4+3]=hv.w;
    }
    float pA0=0.f,pA1=0.f,pA2=0.f,pA3=0.f,pB0=0.f,pB1=0.f,pB2=0.f,pB3=0.f;
    #pragma unroll
    for (int k = 0; k < 8; ++k){
      pA0 = fmaf(wA[k],    hb[k],    pA0); pB0 = fmaf(wB[k],    hb[k],    pB0);
      pA1 = fmaf(wA[k+8],  hb[k+8],  pA1); pB1 = fmaf(wB[k+8],  hb[k+8],  pB1);
      pA2 = fmaf(wA[k+16], hb[k+16], pA2); pB2 = fmaf(wB[k+16], hb[k+16], pB2);
      pA3 = fmaf(wA[k+24], hb[k+24], pA3); pB3 = fmaf(wB[k+24], hb[k+24], pB3);
    }
    float accA = accA0 + ((pA0 + pA1) + (pA2 + pA3));
    float accB = accB0 + ((pB0 + pB1) + (pB2 + pB3));
    float sA = fsig(accA);
    float sB = fmaf(cB, __builtin_amdgcn_rcpf(1.f + __builtin_amdgcn_exp2f(kB * accB)), dB);
    float fs = __shfl_xor(sA, 32, 64);
    float os = __shfl_xor(sB, 32, 64);
    cst = fmaf(fs, cst, sA * sB);
    float h2 = os * ftanh_(cst);
    if (lane < 32){
      hl[lane] = h2;
      if (tau >= tauOut) enc[POS(tau) * 64 + lane] = fsig(h2);
    }
  };

  float pa0, pb0, pa1, pb1;
  { int ip = POS(tau0);     pa0 = xp[ip*128 + lane]; pb0 = xp[ip*128 + 64 + lane]; }
  { int ip = POS(tau0 + 1); pa1 = xp[ip*128 + lane]; pb1 = xp[ip*128 + 64 + lane]; }
  for (int tau = tau0; tau < tauEnd; tau += 2){
    float a0 = pa0, q0 = pb0;
    if (tau + 2 < tauEnd){ int ip = POS(tau + 2); pa0 = xp[ip*128 + lane]; pb0 = xp[ip*128 + 64 + lane]; }
    STEP(a0, q0, tau);
    float a1 = pa1, q1 = pb1;
    if (tau + 3 < tauEnd){ int ip = POS(tau + 3); pa1 = xp[ip*128 + lane]; pb1 = xp[ip*128 + 64 + lane]; }
    STEP(a1, q1, tau + 1);
  }
}

// ---------------- K4: out = f_enc @ e_enc.T  (K=64), 128x128 tiles ----------------
__global__ __launch_bounds__(256) __attribute__((amdgpu_waves_per_eu(2, 4)))
void k_mm(const float* __restrict__ ws, float* __restrict__ out)
{
  const float* e_enc = ws + ENC_OFF;
  const float* f_enc = ws + ENC_OFF + 262144;
  __shared__ __align__(16) float fS[64][128];   // [k][row] — broadcast reads
  __shared__ __align__(16) float eS[64][128];   // [k][col] — contiguous reads
  int t = threadIdx.x;
  int row0 = blockIdx.y * 128;
  int col0 = blockIdx.x * 128;
  {
    int r = t & 127, kh = t >> 7;
    const float* fsrc = f_enc + (size_t)(row0 + r) * 64 + kh * 32;
    const float* esrc = e_enc + (size_t)(col0 + r) * 64 + kh * 32;
    #pragma unroll
    for (int q = 0; q < 8; ++q){
      float4 v = *(const float4*)(fsrc + q * 4);
      int k = kh * 32 + q * 4;
      fS[k+0][r] = v.x; fS[k+1][r] = v.y; fS[k+2][r] = v.z; fS[k+3][r] = v.w;
      float4 u = *(const float4*)(esrc + q * 4);
      eS[k+0][r] = u.x; eS[k+1][r] = u.y; eS[k+2][r] = u.z; eS[k+3][r] = u.w;
    }
  }
  __syncthreads();
  int tx = t & 15, ty = t >> 4;
  int r0 = ty * 8, c0 = tx * 8;
  float acc[8][8];
  #pragma unroll
  for (int i = 0; i < 8; ++i)
    #pragma unroll
    for (int j = 0; j < 8; ++j) acc[i][j] = 0.f;

  #pragma unroll 4
  for (int k = 0; k < 64; ++k){
    float4 fa = *(const float4*)(&fS[k][r0]);
    float4 fb = *(const float4*)(&fS[k][r0 + 4]);
    float4 ea = *(const float4*)(&eS[k][c0]);
    float4 eb = *(const float4*)(&eS[k][c0 + 4]);
    float fr[8] = {fa.x, fa.y, fa.z, fa.w, fb.x, fb.y, fb.z, fb.w};
    float ec[8] = {ea.x, ea.y, ea.z, ea.w, eb.x, eb.y, eb.z, eb.w};
    #pragma unroll
    for (int i = 0; i < 8; ++i)
      #pragma unroll
      for (int j = 0; j < 8; ++j)
        acc[i][j] = fmaf(fr[i], ec[j], acc[i][j]);
  }
  #pragma unroll
  for (int i = 0; i < 8; ++i){
    float* dst = out + (size_t)(row0 + r0 + i) * 4096 + col0 + c0;
    *(float4*)(dst)     = make_float4(acc[i][0], acc[i][1], acc[i][2], acc[i][3]);
    *(float4*)(dst + 4) = make_float4(acc[i][4], acc[i][5], acc[i][6], acc[i][7]);
  }
}

extern "C" void kernel_launch(void* const* d_in, const int* in_sizes, int n_in,
                              void* d_out, int out_size, void* d_ws, size_t ws_size,
                              hipStream_t stream)
{
  const int* e_chars = (const int*)d_in[0];
  const int* e_lens  = (const int*)d_in[1];
  const int* f_chars = (const int*)d_in[2];
  const int* f_lens  = (const int*)d_in[3];
  // d_in[4] = diag (unused by reference)
  const float* embed_e = (const float*)d_in[5];
  const float* embed_f = (const float*)d_in[6];
  const float* eC_ih = (const float*)d_in[7];
  const float* eC_hh = (const float*)d_in[8];
  const float* eC_b  = (const float*)d_in[9];
  const float* fC_ih = (const float*)d_in[10];
  const float* fC_hh = (const float*)d_in[11];
  const float* fC_b  = (const float*)d_in[12];
  const float* efw_ih = (const float*)d_in[13];
  const float* efw_hh = (const float*)d_in[14];
  const float* efw_b  = (const float*)d_in[15];
  const float* ebw_ih = (const float*)d_in[16];
  const float* ebw_hh = (const float*)d_in[17];
  const float* ebw_b  = (const float*)d_in[18];
  const float* ffw_ih = (const float*)d_in[19];
  const float* ffw_hh = (const float*)d_in[20];
  const float* ffw_b  = (const float*)d_in[21];
  const float* fbw_ih = (const float*)d_in[22];
  const float* fbw_hh = (const float*)d_in[23];
  const float* fbw_b  = (const float*)d_in[24];
  float* ws  = (float*)d_ws;
  float* out = (float*)d_out;

  hipLaunchKernelGGL(k_tables, dim3(64, 2), dim3(256), 0, stream,
                     embed_e, embed_f, eC_ih, eC_b, fC_ih, fC_b, ws);
  hipLaunchKernelGGL(k_char, dim3(2048, 2), dim3(128), 0, stream,
                     e_chars, e_lens, f_chars, f_lens, eC_hh, fC_hh, ws);
  hipLaunchKernelGGL(k_proj, dim3(128, 4), dim3(256), 0, stream,
                     efw_ih, efw_b, ebw_ih, ebw_b, ffw_ih, ffw_b, fbw_ih, fbw_b, ws);
  hipLaunchKernelGGL(k_word_par, dim3(kNW / kCL, 4), dim3(64), 0, stream,
                     efw_hh, ebw_hh, ffw_hh, fbw_hh, ws);
  hipLaunchKernelGGL(k_mm, dim3(32, 32), dim3(256), 0, stream, ws, out);
}

// Round 7
// 120.355 us; speedup vs baseline: 5.5236x; 1.0254x over previous
//
#include <hip/hip_runtime.h>

#define kNW 4096
#define kTC 24
#define kCL 4       // outputs per chunk (word-LSTM)
#define kBURN 32    // burn-in steps before each chunk

// ws layout (float offsets)
#define XE_OFF   0u         // [2][128][128]  char input-proj tables (bias folded)
#define WH_OFF   32768u     // [2][4096][32]  char-LSTM final hidden per word
#define XP_OFF   294912u    // [4][4096][128] word-LSTM input projections (bias folded)
#define ENC_OFF  2392064u   // [2][4096][64]  sigmoid(bilstm) encodings

__device__ __forceinline__ float fsig(float x){
  return __builtin_amdgcn_rcpf(1.f + __builtin_amdgcn_exp2f(-1.44269504f * x));
}
__device__ __forceinline__ float ftanh_(float x){
  return fmaf(2.f, __builtin_amdgcn_rcpf(1.f + __builtin_amdgcn_exp2f(-2.88539008f * x)), -1.f);
}

// ---------------- K0: char input-proj tables, coalesced shfl-reduce ----------------
// Wave computes 8 consecutive gates of one (side, char) row: lane-strided loads
// (fully coalesced) + butterfly reduction. Replaces the per-thread sequential
// row walk (64 cache lines per wave load) that kept k_tables at ~40 us.
__global__ __launch_bounds__(256) void k_tables(
    const float* __restrict__ embed_e, const float* __restrict__ embed_f,
    const float* __restrict__ Wih_e, const float* __restrict__ b_e,
    const float* __restrict__ Wih_f, const float* __restrict__ b_f,
    float* __restrict__ ws)
{
  int lane = threadIdx.x & 63;
  int wv   = threadIdx.x >> 6;
  int gw   = blockIdx.x * 4 + wv;            // 0..4095
  int side = gw >> 11;                        // 2048 waves per side
  int c    = (gw & 2047) >> 4;                // 16 waves per char row
  int g0   = (gw & 15) * 8;                   // 8 gates per wave
  const float* er = (side ? embed_f : embed_e) + c * 128;
  const float* Wih = side ? Wih_f : Wih_e;
  const float* bb  = side ? b_f   : b_e;
  float* X = ws + XE_OFF + side * 16384 + c * 128;

  float ea = er[lane], eb = er[lane + 64];
  #pragma unroll
  for (int i = 0; i < 8; ++i){
    const float* wr = Wih + (g0 + i) * 128;
    float p = ea * wr[lane] + eb * wr[lane + 64];
    #pragma unroll
    for (int m = 1; m < 64; m <<= 1) p += __shfl_xor(p, m, 64);
    if (lane == 0) X[g0 + i] = bb[g0 + i] + p;
  }
}

// ---------------- K1: char LSTM, one word per 64-thread block ----------------
// Block = 1 wave = 1 word: retires at its own len (removes max(len1,len2)
// pairing tail). waves_per_eu(2,4) keeps the 64-float weight arrays resident.
__global__ __launch_bounds__(64) __attribute__((amdgpu_waves_per_eu(2, 4)))
void k_char(
    const int* __restrict__ e_chars, const int* __restrict__ e_lens,
    const int* __restrict__ f_chars, const int* __restrict__ f_lens,
    const float* __restrict__ Whh_e, const float* __restrict__ Whh_f,
    float* __restrict__ ws)
{
  int side = blockIdx.y;
  const int* chars = side ? f_chars : e_chars;
  const int* lens  = side ? f_lens  : e_lens;
  const float* Whh = side ? Whh_f : Whh_e;
  const float* X   = ws + XE_OFF + side * 16384;
  float* wh        = ws + WH_OFF + side * 131072;

  int lane = threadIdx.x;
  int word = blockIdx.x;

  __shared__ __align__(16) float hl[32];

  // lane L holds Whh rows L (i or f gate) and L+64 (g or o gate)
  float wA[32], wB[32];
  #pragma unroll
  for (int q = 0; q < 8; ++q){
    float4 a  = *(const float4*)(Whh + lane * 32 + q * 4);
    float4 b4 = *(const float4*)(Whh + (lane + 64) * 32 + q * 4);
    wA[q*4+0]=a.x;  wA[q*4+1]=a.y;  wA[q*4+2]=a.z;  wA[q*4+3]=a.w;
    wB[q*4+0]=b4.x; wB[q*4+1]=b4.y; wB[q*4+2]=b4.z; wB[q*4+3]=b4.w;
  }
  if (lane < 32) hl[lane] = 0.f;
  float cst = 0.f, h2 = 0.f;
  int len = __builtin_amdgcn_readfirstlane(lens[word]);
  float kB = (lane < 32) ? -2.88539008f : -1.44269504f;
  float cB = (lane < 32) ? 2.f : 1.f;
  float dB = (lane < 32) ? -1.f : 0.f;

  int ch0 = __builtin_amdgcn_readfirstlane(chars[word * kTC]);
  float xa = X[ch0 * 128 + lane];
  float xb = X[ch0 * 128 + 64 + lane];

  for (int t = 0; t < len; ++t){
    float accA = xa, accB = xb;
    if (t + 1 < len){
      int cn = __builtin_amdgcn_readfirstlane(chars[word * kTC + t + 1]);
      xa = X[cn * 128 + lane];
      xb = X[cn * 128 + 64 + lane];
    }
    float hb[32];
    #pragma unroll
    for (int q = 0; q < 8; ++q){
      float4 hv = *(const float4*)(&hl[q * 4]);
      hb[q*4+0]=hv.x; hb[q*4+1]=hv.y; hb[q*4+2]=hv.z; hb[q*4+3]=hv.w;
    }
    #pragma unroll
    for (int k = 0; k < 32; ++k){
      accA = fmaf(wA[k], hb[k], accA);
      accB = fmaf(wB[k], hb[k], accB);
    }
    float sA = fsig(accA);
    float sB = fmaf(cB, __builtin_amdgcn_rcpf(1.f + __builtin_amdgcn_exp2f(kB * accB)), dB);
    float fs = __shfl_xor(sA, 32, 64);
    float os = __shfl_xor(sB, 32, 64);
    cst = fmaf(fs, cst, sA * sB);
    h2  = os * ftanh_(cst);
    if (lane < 32) hl[lane] = h2;
  }
  if (lane < 32) wh[word * 32 + lane] = h2;
}

// ---------------- K2: word-LSTM input projections ----------------
__global__ __launch_bounds__(256) __attribute__((amdgpu_waves_per_eu(2, 4)))
void k_proj(
    const float* __restrict__ Wih0, const float* __restrict__ b0,
    const float* __restrict__ Wih1, const float* __restrict__ b1,
    const float* __restrict__ Wih2, const float* __restrict__ b2,
    const float* __restrict__ Wih3, const float* __restrict__ b3,
    float* __restrict__ ws)
{
  int dir = blockIdx.y;
  const float* Wih = dir==0?Wih0 : dir==1?Wih1 : dir==2?Wih2 : Wih3;
  const float* bb  = dir==0?b0  : dir==1?b1  : dir==2?b2  : b3;
  int side = dir >> 1;
  const float* wh = ws + WH_OFF + side * 131072;
  float* xp = ws + XP_OFF + dir * 524288;

  int g  = threadIdx.x & 127;
  int wq = threadIdx.x >> 7;              // 0..1
  int w0 = blockIdx.x * 32 + wq * 16;     // 16 words per half-block

  float wreg[32];
  #pragma unroll
  for (int q = 0; q < 8; ++q){
    float4 v = *(const float4*)(Wih + g * 32 + q * 4);
    wreg[q*4+0]=v.x; wreg[q*4+1]=v.y; wreg[q*4+2]=v.z; wreg[q*4+3]=v.w;
  }
  float bias = bb[g];

  float4 hc[8], hn[8];
  auto LOADH = [&](float4 (&dst)[8], int w){
    const float4* p = (const float4*)(wh + (size_t)w * 32);
    #pragma unroll
    for (int q = 0; q < 8; ++q) dst[q] = p[q];
  };
  auto DOT = [&](const float4 (&hb)[8], int w){
    float acc = bias;
    #pragma unroll
    for (int q = 0; q < 8; ++q){
      acc = fmaf(hb[q].x, wreg[q*4+0], acc);
      acc = fmaf(hb[q].y, wreg[q*4+1], acc);
      acc = fmaf(hb[q].z, wreg[q*4+2], acc);
      acc = fmaf(hb[q].w, wreg[q*4+3], acc);
    }
    xp[(size_t)w * 128 + g] = acc;
  };

  LOADH(hc, w0);
  #pragma unroll
  for (int j = 0; j < 16; j += 2){
    if (j + 1 < 16) LOADH(hn, w0 + j + 1);
    DOT(hc, w0 + j);
    if (j + 1 < 16){
      if (j + 2 < 16) LOADH(hc, w0 + j + 2);
      DOT(hn, w0 + j + 1);
    }
  }
}

// ---------------- K3: word BiLSTM, chunked-parallel with burn-in ----------------
// CL=4/BURN=32 (36 serial steps, 4096 chunks) — parameters validated in round 5.
__global__ __launch_bounds__(64) __attribute__((amdgpu_waves_per_eu(2, 4)))
void k_word_par(
    const float* __restrict__ Whh0, const float* __restrict__ Whh1,
    const float* __restrict__ Whh2, const float* __restrict__ Whh3,
    float* __restrict__ ws)
{
  int qk  = blockIdx.x;              // chunk id 0..1023
  int dir = blockIdx.y;              // 0..3
  const float* Whh = dir==0?Whh0 : dir==1?Whh1 : dir==2?Whh2 : Whh3;
  int side = dir >> 1, bwd = dir & 1;
  const float* xp = ws + XP_OFF + dir * 524288;
  float* enc = ws + ENC_OFF + side * 262144 + (bwd ? 32 : 0);
  int lane = threadIdx.x;

  __shared__ __align__(16) float hl[32];

  float wA[32], wB[32];
  #pragma unroll
  for (int q = 0; q < 8; ++q){
    float4 a  = *(const float4*)(Whh + lane * 32 + q * 4);
    float4 b4 = *(const float4*)(Whh + (lane + 64) * 32 + q * 4);
    wA[q*4+0]=a.x;  wA[q*4+1]=a.y;  wA[q*4+2]=a.z;  wA[q*4+3]=a.w;
    wB[q*4+0]=b4.x; wB[q*4+1]=b4.y; wB[q*4+2]=b4.z; wB[q*4+3]=b4.w;
  }
  if (lane < 32) hl[lane] = 0.f;
  float cst = 0.f;
  float kB = (lane < 32) ? -2.88539008f : -1.44269504f;
  float cB = (lane < 32) ? 2.f : 1.f;
  float dB = (lane < 32) ? -1.f : 0.f;

  int tauOut = qk * kCL;
  int tau0   = tauOut - kBURN; if (tau0 < 0) tau0 = 0;
  int tauEnd = tauOut + kCL;

  auto POS = [&](int tau){ return bwd ? (kNW - 1 - tau) : tau; };

  auto STEP = [&](float accA0, float accB0, int tau){
    float hb[32];
    #pragma unroll
    for (int q = 0; q < 8; ++q){
      float4 hv = *(const float4*)(&hl[q * 4]);
      hb[q*4+0]=hv.x; hb[q*4+1]=hv.y; hb[q*4+2]=hv.z; hb[q*4+3]=hv.w;
    }
    float pA0=0.f,pA1=0.f,pA2=0.f,pA3=0.f,pB0=0.f,pB1=0.f,pB2=0.f,pB3=0.f;
    #pragma unroll
    for (int k = 0; k < 8; ++k){
      pA0 = fmaf(wA[k],    hb[k],    pA0); pB0 = fmaf(wB[k],    hb[k],    pB0);
      pA1 = fmaf(wA[k+8],  hb[k+8],  pA1); pB1 = fmaf(wB[k+8],  hb[k+8],  pB1);
      pA2 = fmaf(wA[k+16], hb[k+16], pA2); pB2 = fmaf(wB[k+16], hb[k+16], pB2);
      pA3 = fmaf(wA[k+24], hb[k+24], pA3); pB3 = fmaf(wB[k+24], hb[k+24], pB3);
    }
    float accA = accA0 + ((pA0 + pA1) + (pA2 + pA3));
    float accB = accB0 + ((pB0 + pB1) + (pB2 + pB3));
    float sA = fsig(accA);
    float sB = fmaf(cB, __builtin_amdgcn_rcpf(1.f + __builtin_amdgcn_exp2f(kB * accB)), dB);
    float fs = __shfl_xor(sA, 32, 64);
    float os = __shfl_xor(sB, 32, 64);
    cst = fmaf(fs, cst, sA * sB);
    float h2 = os * ftanh_(cst);
    if (lane < 32){
      hl[lane] = h2;
      if (tau >= tauOut) enc[POS(tau) * 64 + lane] = fsig(h2);
    }
  };

  float pa0, pb0, pa1, pb1;
  { int ip = POS(tau0);     pa0 = xp[ip*128 + lane]; pb0 = xp[ip*128 + 64 + lane]; }
  { int ip = POS(tau0 + 1); pa1 = xp[ip*128 + lane]; pb1 = xp[ip*128 + 64 + lane]; }
  for (int tau = tau0; tau < tauEnd; tau += 2){
    float a0 = pa0, q0 = pb0;
    if (tau + 2 < tauEnd){ int ip = POS(tau + 2); pa0 = xp[ip*128 + lane]; pb0 = xp[ip*128 + 64 + lane]; }
    STEP(a0, q0, tau);
    float a1 = pa1, q1 = pb1;
    if (tau + 3 < tauEnd){ int ip = POS(tau + 3); pa1 = xp[ip*128 + lane]; pb1 = xp[ip*128 + 64 + lane]; }
    STEP(a1, q1, tau + 1);
  }
}

// ---------------- K4: out = f_enc @ e_enc.T  (K=64), 128x128 tiles ----------------
__global__ __launch_bounds__(256) __attribute__((amdgpu_waves_per_eu(2, 4)))
void k_mm(const float* __restrict__ ws, float* __restrict__ out)
{
  const float* e_enc = ws + ENC_OFF;
  const float* f_enc = ws + ENC_OFF + 262144;
  __shared__ __align__(16) float fS[64][128];   // [k][row] — broadcast reads
  __shared__ __align__(16) float eS[64][128];   // [k][col] — contiguous reads
  int t = threadIdx.x;
  int row0 = blockIdx.y * 128;
  int col0 = blockIdx.x * 128;
  {
    int r = t & 127, kh = t >> 7;
    const float* fsrc = f_enc + (size_t)(row0 + r) * 64 + kh * 32;
    const float* esrc = e_enc + (size_t)(col0 + r) * 64 + kh * 32;
    #pragma unroll
    for (int q = 0; q < 8; ++q){
      float4 v = *(const float4*)(fsrc + q * 4);
      int k = kh * 32 + q * 4;
      fS[k+0][r] = v.x; fS[k+1][r] = v.y; fS[k+2][r] = v.z; fS[k+3][r] = v.w;
      float4 u = *(const float4*)(esrc + q * 4);
      eS[k+0][r] = u.x; eS[k+1][r] = u.y; eS[k+2][r] = u.z; eS[k+3][r] = u.w;
    }
  }
  __syncthreads();
  int tx = t & 15, ty = t >> 4;
  int r0 = ty * 8, c0 = tx * 8;
  float acc[8][8];
  #pragma unroll
  for (int i = 0; i < 8; ++i)
    #pragma unroll
    for (int j = 0; j < 8; ++j) acc[i][j] = 0.f;

  #pragma unroll 4
  for (int k = 0; k < 64; ++k){
    float4 fa = *(const float4*)(&fS[k][r0]);
    float4 fb = *(const float4*)(&fS[k][r0 + 4]);
    float4 ea = *(const float4*)(&eS[k][c0]);
    float4 eb = *(const float4*)(&eS[k][c0 + 4]);
    float fr[8] = {fa.x, fa.y, fa.z, fa.w, fb.x, fb.y, fb.z, fb.w};
    float ec[8] = {ea.x, ea.y, ea.z, ea.w, eb.x, eb.y, eb.z, eb.w};
    #pragma unroll
    for (int i = 0; i < 8; ++i)
      #pragma unroll
      for (int j = 0; j < 8; ++j)
        acc[i][j] = fmaf(fr[i], ec[j], acc[i][j]);
  }
  #pragma unroll
  for (int i = 0; i < 8; ++i){
    float* dst = out + (size_t)(row0 + r0 + i) * 4096 + col0 + c0;
    *(float4*)(dst)     = make_float4(acc[i][0], acc[i][1], acc[i][2], acc[i][3]);
    *(float4*)(dst + 4) = make_float4(acc[i][4], acc[i][5], acc[i][6], acc[i][7]);
  }
}

extern "C" void kernel_launch(void* const* d_in, const int* in_sizes, int n_in,
                              void* d_out, int out_size, void* d_ws, size_t ws_size,
                              hipStream_t stream)
{
  const int* e_chars = (const int*)d_in[0];
  const int* e_lens  = (const int*)d_in[1];
  const int* f_chars = (const int*)d_in[2];
  const int* f_lens  = (const int*)d_in[3];
  // d_in[4] = diag (unused by reference)
  const float* embed_e = (const float*)d_in[5];
  const float* embed_f = (const float*)d_in[6];
  const float* eC_ih = (const float*)d_in[7];
  const float* eC_hh = (const float*)d_in[8];
  const float* eC_b  = (const float*)d_in[9];
  const float* fC_ih = (const float*)d_in[10];
  const float* fC_hh = (const float*)d_in[11];
  const float* fC_b  = (const float*)d_in[12];
  const float* efw_ih = (const float*)d_in[13];
  const float* efw_hh = (const float*)d_in[14];
  const float* efw_b  = (const float*)d_in[15];
  const float* ebw_ih = (const float*)d_in[16];
  const float* ebw_hh = (const float*)d_in[17];
  const float* ebw_b  = (const float*)d_in[18];
  const float* ffw_ih = (const float*)d_in[19];
  const float* ffw_hh = (const float*)d_in[20];
  const float* ffw_b  = (const float*)d_in[21];
  const float* fbw_ih = (const float*)d_in[22];
  const float* fbw_hh = (const float*)d_in[23];
  const float* fbw_b  = (const float*)d_in[24];
  float* ws  = (float*)d_ws;
  float* out = (float*)d_out;

  hipLaunchKernelGGL(k_tables, dim3(1024), dim3(256), 0, stream,
                     embed_e, embed_f, eC_ih, eC_b, fC_ih, fC_b, ws);
  hipLaunchKernelGGL(k_char, dim3(4096, 2), dim3(64), 0, stream,
                     e_chars, e_lens, f_chars, f_lens, eC_hh, fC_hh, ws);
  hipLaunchKernelGGL(k_proj, dim3(128, 4), dim3(256), 0, stream,
                     efw_ih, efw_b, ebw_ih, ebw_b, ffw_ih, ffw_b, fbw_ih, fbw_b, ws);
  hipLaunchKernelGGL(k_word_par, dim3(kNW / kCL, 4), dim3(64), 0, stream,
                     efw_hh, ebw_hh, ffw_hh, fbw_hh, ws);
  hipLaunchKernelGGL(k_mm, dim3(32, 32), dim3(256), 0, stream, ws, out);
}

// Round 8
// 115.024 us; speedup vs baseline: 5.7796x; 1.0463x over previous
//
#include <hip/hip_runtime.h>

#define kNW 4096
#define kTC 24
#define kCL 8       // outputs per chunk (word-LSTM)
#define kBURN 32    // burn-in steps before each chunk

typedef float v2f __attribute__((ext_vector_type(2)));

// ws layout (float offsets)
#define XE_OFF   0u         // [2][128][128]  char input-proj tables (bias folded)
#define WH_OFF   32768u     // [2][4096][32]  char-LSTM final hidden per word
#define XP_OFF   294912u    // [4][4096][128] word-LSTM input projections (bias folded)
#define ENC_OFF  2392064u   // [2][4096][64]  sigmoid(bilstm) encodings

__device__ __forceinline__ float fsig(float x){
  return __builtin_amdgcn_rcpf(1.f + __builtin_amdgcn_exp2f(-1.44269504f * x));
}
__device__ __forceinline__ float ftanh_(float x){
  return fmaf(2.f, __builtin_amdgcn_rcpf(1.f + __builtin_amdgcn_exp2f(-2.88539008f * x)), -1.f);
}

// ---------------- K0: char input-proj tables, coalesced shfl-reduce ----------------
__global__ __launch_bounds__(256) void k_tables(
    const float* __restrict__ embed_e, const float* __restrict__ embed_f,
    const float* __restrict__ Wih_e, const float* __restrict__ b_e,
    const float* __restrict__ Wih_f, const float* __restrict__ b_f,
    float* __restrict__ ws)
{
  int lane = threadIdx.x & 63;
  int wv   = threadIdx.x >> 6;
  int gw   = blockIdx.x * 4 + wv;            // 0..4095
  int side = gw >> 11;                        // 2048 waves per side
  int c    = (gw & 2047) >> 4;                // 16 waves per char row
  int g0   = (gw & 15) * 8;                   // 8 gates per wave
  const float* er = (side ? embed_f : embed_e) + c * 128;
  const float* Wih = side ? Wih_f : Wih_e;
  const float* bb  = side ? b_f   : b_e;
  float* X = ws + XE_OFF + side * 16384 + c * 128;

  float ea = er[lane], eb = er[lane + 64];
  #pragma unroll
  for (int i = 0; i < 8; ++i){
    const float* wr = Wih + (g0 + i) * 128;
    float p = ea * wr[lane] + eb * wr[lane + 64];
    #pragma unroll
    for (int m = 1; m < 64; m <<= 1) p += __shfl_xor(p, m, 64);
    if (lane == 0) X[g0 + i] = bb[g0 + i] + p;
  }
}

// ---------------- K1: char LSTM, one word per 64-thread block ----------------
// pk-f32: dot products as float2 ext-vector fma -> v_pk_fma_f32 (2x f32 issue).
__global__ __launch_bounds__(64) __attribute__((amdgpu_waves_per_eu(2, 4)))
void k_char(
    const int* __restrict__ e_chars, const int* __restrict__ e_lens,
    const int* __restrict__ f_chars, const int* __restrict__ f_lens,
    const float* __restrict__ Whh_e, const float* __restrict__ Whh_f,
    float* __restrict__ ws)
{
  int side = blockIdx.y;
  const int* chars = side ? f_chars : e_chars;
  const int* lens  = side ? f_lens  : e_lens;
  const float* Whh = side ? Whh_f : Whh_e;
  const float* X   = ws + XE_OFF + side * 16384;
  float* wh        = ws + WH_OFF + side * 131072;

  int lane = threadIdx.x;
  int word = blockIdx.x;

  __shared__ __align__(16) float hl[32];

  // lane L holds Whh rows L (i or f gate) and L+64 (g or o gate), as float2 pairs
  v2f wA[16], wB[16];
  #pragma unroll
  for (int q = 0; q < 8; ++q){
    float4 a  = *(const float4*)(Whh + lane * 32 + q * 4);
    float4 b4 = *(const float4*)(Whh + (lane + 64) * 32 + q * 4);
    wA[q*2+0] = (v2f){a.x, a.y};  wA[q*2+1] = (v2f){a.z, a.w};
    wB[q*2+0] = (v2f){b4.x, b4.y}; wB[q*2+1] = (v2f){b4.z, b4.w};
  }
  if (lane < 32) hl[lane] = 0.f;
  float cst = 0.f, h2 = 0.f;
  int len = __builtin_amdgcn_readfirstlane(lens[word]);
  float kB = (lane < 32) ? -2.88539008f : -1.44269504f;
  float cB = (lane < 32) ? 2.f : 1.f;
  float dB = (lane < 32) ? -1.f : 0.f;

  int ch0 = __builtin_amdgcn_readfirstlane(chars[word * kTC]);
  float xa = X[ch0 * 128 + lane];
  float xb = X[ch0 * 128 + 64 + lane];

  for (int t = 0; t < len; ++t){
    float accA0 = xa, accB0 = xb;
    if (t + 1 < len){
      int cn = __builtin_amdgcn_readfirstlane(chars[word * kTC + t + 1]);
      xa = X[cn * 128 + lane];
      xb = X[cn * 128 + 64 + lane];
    }
    v2f hb[16];
    #pragma unroll
    for (int q = 0; q < 8; ++q){
      float4 hv = *(const float4*)(&hl[q * 4]);
      hb[q*2+0] = (v2f){hv.x, hv.y}; hb[q*2+1] = (v2f){hv.z, hv.w};
    }
    v2f qa0 = {0.f,0.f}, qa1 = {0.f,0.f}, qb0 = {0.f,0.f}, qb1 = {0.f,0.f};
    #pragma unroll
    for (int k = 0; k < 8; ++k){
      qa0 = __builtin_elementwise_fma(wA[k],   hb[k],   qa0);
      qa1 = __builtin_elementwise_fma(wA[k+8], hb[k+8], qa1);
      qb0 = __builtin_elementwise_fma(wB[k],   hb[k],   qb0);
      qb1 = __builtin_elementwise_fma(wB[k+8], hb[k+8], qb1);
    }
    float accA = accA0 + ((qa0.x + qa0.y) + (qa1.x + qa1.y));
    float accB = accB0 + ((qb0.x + qb0.y) + (qb1.x + qb1.y));
    float sA = fsig(accA);
    float sB = fmaf(cB, __builtin_amdgcn_rcpf(1.f + __builtin_amdgcn_exp2f(kB * accB)), dB);
    float fs = __shfl_xor(sA, 32, 64);
    float os = __shfl_xor(sB, 32, 64);
    cst = fmaf(fs, cst, sA * sB);
    h2  = os * ftanh_(cst);
    if (lane < 32) hl[lane] = h2;
  }
  if (lane < 32) wh[word * 32 + lane] = h2;
}

// ---------------- K2: word-LSTM input projections ----------------
__global__ __launch_bounds__(256) __attribute__((amdgpu_waves_per_eu(2, 4)))
void k_proj(
    const float* __restrict__ Wih0, const float* __restrict__ b0,
    const float* __restrict__ Wih1, const float* __restrict__ b1,
    const float* __restrict__ Wih2, const float* __restrict__ b2,
    const float* __restrict__ Wih3, const float* __restrict__ b3,
    float* __restrict__ ws)
{
  int dir = blockIdx.y;
  const float* Wih = dir==0?Wih0 : dir==1?Wih1 : dir==2?Wih2 : Wih3;
  const float* bb  = dir==0?b0  : dir==1?b1  : dir==2?b2  : b3;
  int side = dir >> 1;
  const float* wh = ws + WH_OFF + side * 131072;
  float* xp = ws + XP_OFF + dir * 524288;

  int g  = threadIdx.x & 127;
  int wq = threadIdx.x >> 7;              // 0..1
  int w0 = blockIdx.x * 32 + wq * 16;     // 16 words per half-block

  float wreg[32];
  #pragma unroll
  for (int q = 0; q < 8; ++q){
    float4 v = *(const float4*)(Wih + g * 32 + q * 4);
    wreg[q*4+0]=v.x; wreg[q*4+1]=v.y; wreg[q*4+2]=v.z; wreg[q*4+3]=v.w;
  }
  float bias = bb[g];

  float4 hc[8], hn[8];
  auto LOADH = [&](float4 (&dst)[8], int w){
    const float4* p = (const float4*)(wh + (size_t)w * 32);
    #pragma unroll
    for (int q = 0; q < 8; ++q) dst[q] = p[q];
  };
  auto DOT = [&](const float4 (&hb)[8], int w){
    float acc = bias;
    #pragma unroll
    for (int q = 0; q < 8; ++q){
      acc = fmaf(hb[q].x, wreg[q*4+0], acc);
      acc = fmaf(hb[q].y, wreg[q*4+1], acc);
      acc = fmaf(hb[q].z, wreg[q*4+2], acc);
      acc = fmaf(hb[q].w, wreg[q*4+3], acc);
    }
    xp[(size_t)w * 128 + g] = acc;
  };

  LOADH(hc, w0);
  #pragma unroll
  for (int j = 0; j < 16; j += 2){
    if (j + 1 < 16) LOADH(hn, w0 + j + 1);
    DOT(hc, w0 + j);
    if (j + 1 < 16){
      if (j + 2 < 16) LOADH(hc, w0 + j + 2);
      DOT(hn, w0 + j + 1);
    }
  }
}

// ---------------- K3: word BiLSTM, chunked-parallel with burn-in ----------------
// CL=8/BURN=32: 2048 one-wave blocks x 40 steps (1.8x less scan issue than CL=4),
// 2 waves/SIMD balanced. pk-f32 FMA in the matvec.
__global__ __launch_bounds__(64) __attribute__((amdgpu_waves_per_eu(2, 4)))
void k_word_par(
    const float* __restrict__ Whh0, const float* __restrict__ Whh1,
    const float* __restrict__ Whh2, const float* __restrict__ Whh3,
    float* __restrict__ ws)
{
  int qk  = blockIdx.x;              // chunk id 0..511
  int dir = blockIdx.y;              // 0..3
  const float* Whh = dir==0?Whh0 : dir==1?Whh1 : dir==2?Whh2 : Whh3;
  int side = dir >> 1, bwd = dir & 1;
  const float* xp = ws + XP_OFF + dir * 524288;
  float* enc = ws + ENC_OFF + side * 262144 + (bwd ? 32 : 0);
  int lane = threadIdx.x;

  __shared__ __align__(16) float hl[32];

  v2f wA[16], wB[16];
  #pragma unroll
  for (int q = 0; q < 8; ++q){
    float4 a  = *(const float4*)(Whh + lane * 32 + q * 4);
    float4 b4 = *(const float4*)(Whh + (lane + 64) * 32 + q * 4);
    wA[q*2+0] = (v2f){a.x, a.y};  wA[q*2+1] = (v2f){a.z, a.w};
    wB[q*2+0] = (v2f){b4.x, b4.y}; wB[q*2+1] = (v2f){b4.z, b4.w};
  }
  if (lane < 32) hl[lane] = 0.f;
  float cst = 0.f;
  float kB = (lane < 32) ? -2.88539008f : -1.44269504f;
  float cB = (lane < 32) ? 2.f : 1.f;
  float dB = (lane < 32) ? -1.f : 0.f;

  int tauOut = qk * kCL;
  int tau0   = tauOut - kBURN; if (tau0 < 0) tau0 = 0;
  int tauEnd = tauOut + kCL;

  auto POS = [&](int tau){ return bwd ? (kNW - 1 - tau) : tau; };

  auto STEP = [&](float accA0, float accB0, int tau){
    v2f hb[16];
    #pragma unroll
    for (int q = 0; q < 8; ++q){
      float4 hv = *(const float4*)(&hl[q * 4]);
      hb[q*2+0] = (v2f){hv.x, hv.y}; hb[q*2+1] = (v2f){hv.z, hv.w};
    }
    v2f qa0 = {0.f,0.f}, qa1 = {0.f,0.f}, qb0 = {0.f,0.f}, qb1 = {0.f,0.f};
    #pragma unroll
    for (int k = 0; k < 8; ++k){
      qa0 = __builtin_elementwise_fma(wA[k],   hb[k],   qa0);
      qa1 = __builtin_elementwise_fma(wA[k+8], hb[k+8], qa1);
      qb0 = __builtin_elementwise_fma(wB[k],   hb[k],   qb0);
      qb1 = __builtin_elementwise_fma(wB[k+8], hb[k+8], qb1);
    }
    float accA = accA0 + ((qa0.x + qa0.y) + (qa1.x + qa1.y));
    float accB = accB0 + ((qb0.x + qb0.y) + (qb1.x + qb1.y));
    float sA = fsig(accA);
    float sB = fmaf(cB, __builtin_amdgcn_rcpf(1.f + __builtin_amdgcn_exp2f(kB * accB)), dB);
    float fs = __shfl_xor(sA, 32, 64);
    float os = __shfl_xor(sB, 32, 64);
    cst = fmaf(fs, cst, sA * sB);
    float h2 = os * ftanh_(cst);
    if (lane < 32){
      hl[lane] = h2;
      if (tau >= tauOut) enc[POS(tau) * 64 + lane] = fsig(h2);
    }
  };

  float pa0, pb0, pa1, pb1;
  { int ip = POS(tau0);     pa0 = xp[ip*128 + lane]; pb0 = xp[ip*128 + 64 + lane]; }
  { int ip = POS(tau0 + 1); pa1 = xp[ip*128 + lane]; pb1 = xp[ip*128 + 64 + lane]; }
  for (int tau = tau0; tau < tauEnd; tau += 2){
    float a0 = pa0, q0 = pb0;
    if (tau + 2 < tauEnd){ int ip = POS(tau + 2); pa0 = xp[ip*128 + lane]; pb0 = xp[ip*128 + 64 + lane]; }
    STEP(a0, q0, tau);
    float a1 = pa1, q1 = pb1;
    if (tau + 3 < tauEnd){ int ip = POS(tau + 3); pa1 = xp[ip*128 + lane]; pb1 = xp[ip*128 + 64 + lane]; }
    STEP(a1, q1, tau + 1);
  }
}

// ---------------- K4: out = f_enc @ e_enc.T  (K=64), 128x128 tiles, pk-f32 ----------------
__global__ __launch_bounds__(256) __attribute__((amdgpu_waves_per_eu(2, 4)))
void k_mm(const float* __restrict__ ws, float* __restrict__ out)
{
  const float* e_enc = ws + ENC_OFF;
  const float* f_enc = ws + ENC_OFF + 262144;
  __shared__ __align__(16) float fS[64][128];   // [k][row] — broadcast reads
  __shared__ __align__(16) float eS[64][128];   // [k][col] — contiguous reads
  int t = threadIdx.x;
  int row0 = blockIdx.y * 128;
  int col0 = blockIdx.x * 128;
  {
    int r = t & 127, kh = t >> 7;
    const float* fsrc = f_enc + (size_t)(row0 + r) * 64 + kh * 32;
    const float* esrc = e_enc + (size_t)(col0 + r) * 64 + kh * 32;
    #pragma unroll
    for (int q = 0; q < 8; ++q){
      float4 v = *(const float4*)(fsrc + q * 4);
      int k = kh * 32 + q * 4;
      fS[k+0][r] = v.x; fS[k+1][r] = v.y; fS[k+2][r] = v.z; fS[k+3][r] = v.w;
      float4 u = *(const float4*)(esrc + q * 4);
      eS[k+0][r] = u.x; eS[k+1][r] = u.y; eS[k+2][r] = u.z; eS[k+3][r] = u.w;
    }
  }
  __syncthreads();
  int tx = t & 15, ty = t >> 4;
  int r0 = ty * 8, c0 = tx * 8;
  v2f acc2[8][4];
  #pragma unroll
  for (int i = 0; i < 8; ++i)
    #pragma unroll
    for (int j = 0; j < 4; ++j) acc2[i][j] = (v2f){0.f, 0.f};

  #pragma unroll 4
  for (int k = 0; k < 64; ++k){
    float4 fa = *(const float4*)(&fS[k][r0]);
    float4 fb = *(const float4*)(&fS[k][r0 + 4]);
    float4 ea = *(const float4*)(&eS[k][c0]);
    float4 eb = *(const float4*)(&eS[k][c0 + 4]);
    float fr[8] = {fa.x, fa.y, fa.z, fa.w, fb.x, fb.y, fb.z, fb.w};
    v2f e2[4] = {(v2f){ea.x, ea.y}, (v2f){ea.z, ea.w},
                 (v2f){eb.x, eb.y}, (v2f){eb.z, eb.w}};
    #pragma unroll
    for (int i = 0; i < 8; ++i){
      v2f f2 = (v2f){fr[i], fr[i]};
      #pragma unroll
      for (int j = 0; j < 4; ++j)
        acc2[i][j] = __builtin_elementwise_fma(f2, e2[j], acc2[i][j]);
    }
  }
  #pragma unroll
  for (int i = 0; i < 8; ++i){
    float* dst = out + (size_t)(row0 + r0 + i) * 4096 + col0 + c0;
    *(float4*)(dst)     = make_float4(acc2[i][0].x, acc2[i][0].y, acc2[i][1].x, acc2[i][1].y);
    *(float4*)(dst + 4) = make_float4(acc2[i][2].x, acc2[i][2].y, acc2[i][3].x, acc2[i][3].y);
  }
}

extern "C" void kernel_launch(void* const* d_in, const int* in_sizes, int n_in,
                              void* d_out, int out_size, void* d_ws, size_t ws_size,
                              hipStream_t stream)
{
  const int* e_chars = (const int*)d_in[0];
  const int* e_lens  = (const int*)d_in[1];
  const int* f_chars = (const int*)d_in[2];
  const int* f_lens  = (const int*)d_in[3];
  // d_in[4] = diag (unused by reference)
  const float* embed_e = (const float*)d_in[5];
  const float* embed_f = (const float*)d_in[6];
  const float* eC_ih = (const float*)d_in[7];
  const float* eC_hh = (const float*)d_in[8];
  const float* eC_b  = (const float*)d_in[9];
  const float* fC_ih = (const float*)d_in[10];
  const float* fC_hh = (const float*)d_in[11];
  const float* fC_b  = (const float*)d_in[12];
  const float* efw_ih = (const float*)d_in[13];
  const float* efw_hh = (const float*)d_in[14];
  const float* efw_b  = (const float*)d_in[15];
  const float* ebw_ih = (const float*)d_in[16];
  const float* ebw_hh = (const float*)d_in[17];
  const float* ebw_b  = (const float*)d_in[18];
  const float* ffw_ih = (const float*)d_in[19];
  const float* ffw_hh = (const float*)d_in[20];
  const float* ffw_b  = (const float*)d_in[21];
  const float* fbw_ih = (const float*)d_in[22];
  const float* fbw_hh = (const float*)d_in[23];
  const float* fbw_b  = (const float*)d_in[24];
  float* ws  = (float*)d_ws;
  float* out = (float*)d_out;

  hipLaunchKernelGGL(k_tables, dim3(1024), dim3(256), 0, stream,
                     embed_e, embed_f, eC_ih, eC_b, fC_ih, fC_b, ws);
  hipLaunchKernelGGL(k_char, dim3(4096, 2), dim3(64), 0, stream,
                     e_chars, e_lens, f_chars, f_lens, eC_hh, fC_hh, ws);
  hipLaunchKernelGGL(k_proj, dim3(128, 4), dim3(256), 0, stream,
                     efw_ih, efw_b, ebw_ih, ebw_b, ffw_ih, ffw_b, fbw_ih, fbw_b, ws);
  hipLaunchKernelGGL(k_word_par, dim3(kNW / kCL, 4), dim3(64), 0, stream,
                     efw_hh, ebw_hh, ffw_hh, fbw_hh, ws);
  hipLaunchKernelGGL(k_mm, dim3(32, 32), dim3(256), 0, stream, ws, out);
}